// Round 6
// baseline (71.348 us; speedup 1.0000x reference)
//
#include <hip/hip_runtime.h>
#include <hip/hip_bf16.h>

#define B_ROWS 8192
#define E_DIM  1024
#define MARGIN 0.2f

#define BM 256
#define BN 256
#define BK 64
#define KSPLIT 2
#define KHALF (E_DIM / KSPLIT)   // 512
#define NT (KHALF / BK)          // 8 K-tiles per block

typedef __bf16 bf16x8 __attribute__((ext_vector_type(8)));
typedef float  f32x4  __attribute__((ext_vector_type(4)));

__device__ __forceinline__ void gload_lds16(const void* g, void* l) {
    __builtin_amdgcn_global_load_lds(
        (__attribute__((address_space(1))) void*)(g),
        (__attribute__((address_space(3))) void*)(l),
        16, 0, 0);
}

// c = 0.4*m + 0.6*tr_m, fp32 -> bf16 (BW-bound, ~13 us)
__global__ void prep_c(const float* __restrict__ m, const float* __restrict__ trm,
                       __bf16* __restrict__ c) {
    size_t i = ((size_t)blockIdx.x * blockDim.x + threadIdx.x) * 8;
    float4 m0 = *(const float4*)(m + i);
    float4 m1 = *(const float4*)(m + i + 4);
    float4 t0 = *(const float4*)(trm + i);
    float4 t1 = *(const float4*)(trm + i + 4);
    bf16x8 v;
    v[0] = (__bf16)(0.4f*m0.x + 0.6f*t0.x);
    v[1] = (__bf16)(0.4f*m0.y + 0.6f*t0.y);
    v[2] = (__bf16)(0.4f*m0.z + 0.6f*t0.z);
    v[3] = (__bf16)(0.4f*m0.w + 0.6f*t0.w);
    v[4] = (__bf16)(0.4f*m1.x + 0.6f*t1.x);
    v[5] = (__bf16)(0.4f*m1.y + 0.6f*t1.y);
    v[6] = (__bf16)(0.4f*m1.z + 0.6f*t1.z);
    v[7] = (__bf16)(0.4f*m1.w + 0.6f*t1.w);
    *(bf16x8*)(c + i) = v;
}

// Wt[n][e] = bf16(W[e][n])
__global__ void transpose_w(const float* __restrict__ W, __bf16* __restrict__ Wt) {
    __shared__ __bf16 tile[32][33];
    int tx = threadIdx.x, ty = threadIdx.y;
    int bx = blockIdx.x * 32;
    int by = blockIdx.y * 32;
    tile[ty][tx] = (__bf16)W[(size_t)(by + ty) * E_DIM + bx + tx];
    __syncthreads();
    Wt[(size_t)(bx + ty) * E_DIM + by + tx] = tile[tx][ty];
}

// ---- 8-phase-style pipelined GEMM (T3+T4+T5), 256x256, BK=64, split-K=2 ----
// Ring of 8 stage-units (2 tilebuf x 2 khalf x {A,B}), 16 KiB each.
// Unit layout [blk:16][kc:4][r15:16][16B]: frag read addr = base + lane*16
// (lane-linear, conflict-free); the permutation is applied on the per-lane
// GLOBAL source address of global_load_lds (linear LDS dest, rule #21).
// Per K-tile: 4 phases; each phase: {ds_reads | stage 1 unit | bar |
// lgkm(0) | 16 MFMA (setprio) | [vmcnt gate] | bar}.
// Stage schedule per tile t: ph0:A(t+1,kh1) ph1:B(t+1,kh1) ph2:A(t+2,kh0)
// ph3:B(t+2,kh0). Unit written at phase p was last read >=1 barrier earlier.
// Gates (counted, never drained mid-loop): end-ph1 vmcnt(8) certifies
// (t,kh1); end-ph3 vmcnt(8) certifies (t+1,kh0). Tail: 8 -> 4 -> 0.

#define BAR()   asm volatile("s_barrier" ::: "memory")
#define LGKM0() do { asm volatile("s_waitcnt lgkmcnt(0)" ::: "memory"); \
                     __builtin_amdgcn_sched_barrier(0); } while (0)

#define MFMA16(AARR, BARR, MOFF)                                              \
    __builtin_amdgcn_s_setprio(1);                                            \
    _Pragma("unroll")                                                         \
    for (int mi_ = 0; mi_ < 4; ++mi_) {                                       \
        _Pragma("unroll")                                                     \
        for (int ni_ = 0; ni_ < 4; ++ni_)                                     \
            acc[(MOFF) + mi_][ni_] = __builtin_amdgcn_mfma_f32_16x16x32_bf16( \
                AARR[mi_], BARR[ni_], acc[(MOFF) + mi_][ni_], 0, 0, 0);       \
    }                                                                         \
    __builtin_amdgcn_s_setprio(0);

#define TILE(T, S01, S23, G1, G3HAS, G3)                                      \
    {                                                                         \
        const int slot_ = (T) & 1;                                            \
        bf16x8 a0[4], a1[4], b0[4], b1[4];                                    \
        /* ---- ph0: kh0, mi 0-3 ---- */                                      \
        _Pragma("unroll") for (int q = 0; q < 4; ++q) b0[q] = rdB(slot_,0,q); \
        _Pragma("unroll") for (int q = 0; q < 4; ++q) a0[q] = rdA(slot_,0,q); \
        if (S01) stageA((T) + 1, 1);                                          \
        BAR(); LGKM0();                                                       \
        MFMA16(a0, b0, 0)                                                     \
        BAR();                                                                \
        /* ---- ph1: kh0, mi 4-7 ---- */                                      \
        _Pragma("unroll") for (int q = 0; q < 4; ++q) a1[q] = rdA(slot_,0,4+q);\
        if (S01) stageB((T) + 1, 1);                                          \
        BAR(); LGKM0();                                                       \
        MFMA16(a1, b0, 4)                                                     \
        asm volatile("s_waitcnt vmcnt(" G1 ")" ::: "memory");                 \
        BAR();                                                                \
        /* ---- ph2: kh1, mi 0-3 ---- */                                      \
        _Pragma("unroll") for (int q = 0; q < 4; ++q) b1[q] = rdB(slot_,1,q); \
        _Pragma("unroll") for (int q = 0; q < 4; ++q) a0[q] = rdA(slot_,1,q); \
        if (S23) stageA((T) + 2, 0);                                          \
        BAR(); LGKM0();                                                       \
        MFMA16(a0, b1, 0)                                                     \
        BAR();                                                                \
        /* ---- ph3: kh1, mi 4-7 ---- */                                      \
        _Pragma("unroll") for (int q = 0; q < 4; ++q) a1[q] = rdA(slot_,1,4+q);\
        if (S23) stageB((T) + 2, 0);                                          \
        BAR(); LGKM0();                                                       \
        MFMA16(a1, b1, 4)                                                     \
        if (G3HAS) { asm volatile("s_waitcnt vmcnt(" G3 ")" ::: "memory"); }  \
        BAR();                                                                \
    }

__global__ __launch_bounds__(512, 2)
void gemm_dot(const __bf16* __restrict__ Cm, const __bf16* __restrict__ Wt,
              const float* __restrict__ Ais, const float* __restrict__ Aem,
              float* __restrict__ delta) {
    __shared__ __bf16 AL[2][2][8192];   // [tilebuf][khalf][16 KiB unit]
    __shared__ __bf16 BL[2][2][8192];

    const int tid  = threadIdx.x;
    const int lane = tid & 63;
    const int lr   = lane & 15;
    const int hi   = lane >> 4;
    const int wave = tid >> 6;     // 0..7
    const int wr   = wave >> 2;    // M half
    const int wc   = wave & 3;     // N quarter

    // XCD swizzle: xcd owns 4 row-panels x 4 colb x 2 ksplit = 32 blocks;
    // per-XCD L2 set = 4 c-panels (2 MiB) + Wt (2 MiB).
    const int bid = blockIdx.x;
    const int xcd = bid & 7;
    const int j   = bid >> 3;
    const int sub = j & 7;
    const int rb    = (xcd * 4 + (j >> 3)) * BM;
    const int cbN   = (sub & 3) * BN;
    const int kbase = (sub >> 2) * KHALF;

    // stage one 16-KiB unit: idx bits [3:0]=r15 [5:4]=kc [9:6]=blk
    auto stageA = [&](int t, int kh) {
        char* base = (char*)&AL[t & 1][kh][0];
        const size_t k0b = (size_t)(kbase + t * BK + kh * 32) * 2;
#pragma unroll
        for (int i = 0; i < 2; ++i) {
            const int idx = i * 512 + tid;
            const int r   = rb + (idx >> 6) * 16 + (idx & 15);
            gload_lds16((const char*)Cm + (size_t)r * (E_DIM * 2) + k0b + ((idx >> 4) & 3) * 16,
                        base + idx * 16);
        }
    };
    auto stageB = [&](int t, int kh) {
        char* base = (char*)&BL[t & 1][kh][0];
        const size_t k0b = (size_t)(kbase + t * BK + kh * 32) * 2;
#pragma unroll
        for (int i = 0; i < 2; ++i) {
            const int idx = i * 512 + tid;
            const int r   = cbN + (idx >> 6) * 16 + (idx & 15);
            gload_lds16((const char*)Wt + (size_t)r * (E_DIM * 2) + k0b + ((idx >> 4) & 3) * 16,
                        base + idx * 16);
        }
    };

    // frag reads: lane-linear (base + lane*16) -> zero bank conflicts
    auto rdA = [&](int slot, int kh, int mi) {
        return *(const bf16x8*)((const char*)&AL[slot][kh][0] +
                                (wr * 8 + mi) * 1024 + lane * 16);
    };
    auto rdB = [&](int slot, int kh, int ni) {
        return *(const bf16x8*)((const char*)&BL[slot][kh][0] +
                                (wc * 4 + ni) * 1024 + lane * 16);
    };

    f32x4 acc[8][4] = {};

    // prologue: 6 units in issue order; vmcnt(8) => A(0,0),B(0,0) landed
    stageA(0, 0); stageB(0, 0); stageA(0, 1); stageB(0, 1); stageA(1, 0); stageB(1, 0);
    asm volatile("s_waitcnt vmcnt(8)" ::: "memory");
    BAR();

    for (int t = 0; t < NT - 2; ++t)   // t = 0..5: fully regular
        TILE(t, 1, 1, "8", 1, "8")
    TILE(NT - 2, 1, 0, "8", 1, "4")    // t=6: stage only (7,kh1); tail gate 4
    TILE(NT - 1, 0, 0, "0", 0, "0")    // t=7: no stage; gate 0 for own kh1

    // epilogue: delta[r] += sum_col u[r][col] * (Ais - Aem)[r][col]
    // C/D layout: col = lane&15, row = (lane>>4)*4 + reg
    const int colbase = cbN + wc * 64 + lr;
    const int rowb    = rb + wr * 128 + hi * 4;
#pragma unroll
    for (int mi = 0; mi < 8; ++mi) {
#pragma unroll
        for (int jj = 0; jj < 4; ++jj) {
            const int r = rowb + mi * 16 + jj;
            float v = 0.f;
#pragma unroll
            for (int ni = 0; ni < 4; ++ni) {
                const size_t idx = (size_t)r * E_DIM + colbase + ni * 16;
                v += acc[mi][ni][jj] * (Ais[idx] - Aem[idx]);
            }
            v += __shfl_xor(v, 1);
            v += __shfl_xor(v, 2);
            v += __shfl_xor(v, 4);
            v += __shfl_xor(v, 8);
            if (lr == 0) atomicAdd(&delta[r], v);
        }
    }
}

__global__ void hinge_sum(const float* __restrict__ delta, float* __restrict__ out) {
    float s = 0.f;
    for (int i = threadIdx.x; i < B_ROWS; i += 256)
        s += fmaxf(MARGIN + delta[i], 0.f);
#pragma unroll
    for (int off = 32; off > 0; off >>= 1) s += __shfl_down(s, off);
    __shared__ float wsum[4];
    int lane = threadIdx.x & 63, w = threadIdx.x >> 6;
    if (lane == 0) wsum[w] = s;
    __syncthreads();
    if (threadIdx.x == 0) out[0] = wsum[0] + wsum[1] + wsum[2] + wsum[3];
}

extern "C" void kernel_launch(void* const* d_in, const int* in_sizes, int n_in,
                              void* d_out, int out_size, void* d_ws, size_t ws_size,
                              hipStream_t stream) {
    const float* A_is = (const float*)d_in[0];
    const float* A_em = (const float*)d_in[1];
    const float* m    = (const float*)d_in[2];
    const float* tr_m = (const float*)d_in[3];
    const float* W    = (const float*)d_in[4];
    // d_in[5] = b : cancels in diag_is - diag_em, unused.
    float* out = (float*)d_out;

    char* ws = (char*)d_ws;
    __bf16* c     = (__bf16*)ws;                              // 16 MiB
    __bf16* wt    = (__bf16*)(ws + (size_t)16 * 1024 * 1024); //  2 MiB
    float*  delta = (float*) (ws + (size_t)18 * 1024 * 1024); // 32 KiB

    hipMemsetAsync(delta, 0, B_ROWS * sizeof(float), stream);
    prep_c<<<4096, 256, 0, stream>>>(m, tr_m, c);
    transpose_w<<<dim3(32, 32), dim3(32, 32), 0, stream>>>(W, wt);
    gemm_dot<<<256, 512, 0, stream>>>(c, wt, A_is, A_em, delta);
    hinge_sum<<<1, 256, 0, stream>>>(delta, out);
}

// Round 7
// 66.077 us; speedup vs baseline: 1.0798x; 1.0798x over previous
//
#include <hip/hip_runtime.h>
#include <hip/hip_bf16.h>

#define B_ROWS 8192
#define E_DIM  1024
#define MARGIN 0.2f

#define BM 128
#define BN 128
#define BK 32
#define NSTEPS (E_DIM / BK)   // 32

typedef __bf16 bf16x8 __attribute__((ext_vector_type(8)));
typedef float  f32x4  __attribute__((ext_vector_type(4)));

__device__ __forceinline__ void gload_lds16(const void* g, void* l) {
    __builtin_amdgcn_global_load_lds(
        (__attribute__((address_space(1))) void*)(g),
        (__attribute__((address_space(3))) void*)(l),
        16, 0, 0);
}

// c = 0.4*m + 0.6*tr_m, fp32 -> bf16 (BW-bound, ~13 us)
__global__ void prep_c(const float* __restrict__ m, const float* __restrict__ trm,
                       __bf16* __restrict__ c) {
    size_t i = ((size_t)blockIdx.x * blockDim.x + threadIdx.x) * 8;
    float4 m0 = *(const float4*)(m + i);
    float4 m1 = *(const float4*)(m + i + 4);
    float4 t0 = *(const float4*)(trm + i);
    float4 t1 = *(const float4*)(trm + i + 4);
    bf16x8 v;
    v[0] = (__bf16)(0.4f*m0.x + 0.6f*t0.x);
    v[1] = (__bf16)(0.4f*m0.y + 0.6f*t0.y);
    v[2] = (__bf16)(0.4f*m0.z + 0.6f*t0.z);
    v[3] = (__bf16)(0.4f*m0.w + 0.6f*t0.w);
    v[4] = (__bf16)(0.4f*m1.x + 0.6f*t1.x);
    v[5] = (__bf16)(0.4f*m1.y + 0.6f*t1.y);
    v[6] = (__bf16)(0.4f*m1.z + 0.6f*t1.z);
    v[7] = (__bf16)(0.4f*m1.w + 0.6f*t1.w);
    *(bf16x8*)(c + i) = v;
}

// Wt[n][e] = bf16(W[e][n])
__global__ void transpose_w(const float* __restrict__ W, __bf16* __restrict__ Wt) {
    __shared__ __bf16 tile[32][33];
    int tx = threadIdx.x, ty = threadIdx.y;
    int bx = blockIdx.x * 32;
    int by = blockIdx.y * 32;
    tile[ty][tx] = (__bf16)W[(size_t)(by + ty) * E_DIM + bx + tx];
    __syncthreads();
    Wt[(size_t)(bx + ty) * E_DIM + by + tx] = tile[tx][ty];
}

// Pure GEMM: u = c @ Wt^T, bf16 out. R4's proven 2-phase 128x128/BK=32 loop
// (both operands via global_load_lds, prefetch issued before compute, one
// barrier per K-step), full K=1024, grid 512 = 8 xcd x (8 panels x 8 colb).
__global__ __launch_bounds__(256)
void gemm_u(const __bf16* __restrict__ Cm, const __bf16* __restrict__ Wt,
            __bf16* __restrict__ u) {
    __shared__ __bf16 As[2][BM * BK];   // 2 x 8 KiB, linear
    __shared__ __bf16 Bs[2][BN * BK];   // 2 x 8 KiB, linear

    const int tid  = threadIdx.x;
    const int lane = tid & 63;
    const int wave = tid >> 6;
    const int lr   = lane & 15;
    const int hi   = lane >> 4;
    const int wr   = wave >> 1, wc = wave & 1;

    // XCD swizzle: xcd owns 8 row-panels x all 8 colb ->
    // per-XCD L2 set = 8 c-panels (2 MiB) + Wt (2 MiB).
    const int bid   = blockIdx.x;
    const int xcd   = bid & 7;
    const int q     = bid >> 3;          // 0..63
    const int colb  = q & 7;
    const int rb    = (xcd * 8 + (q >> 3)) * BM;
    const int cb    = colb * BN;

    auto stage = [&](int buf, int k0) {
#pragma unroll
        for (int i = 0; i < 2; ++i) {
            int off = i * 4096 + tid * 16;   // byte offset in 8 KiB tile
            int row = off >> 6;              // 64 B per 32-bf16 row
            int kb  = off & 63;
            gload_lds16((const char*)Cm + ((size_t)(rb + row) * E_DIM + k0) * 2 + kb,
                        (char*)(&As[buf][0]) + off);
            gload_lds16((const char*)Wt + ((size_t)(cb + row) * E_DIM + k0) * 2 + kb,
                        (char*)(&Bs[buf][0]) + off);
        }
    };

    f32x4 acc[4][4] = {};

    stage(0, 0);
    __syncthreads();

    int cur = 0;
    for (int t = 0; t < NSTEPS; ++t) {
        if (t + 1 < NSTEPS) stage(cur ^ 1, (t + 1) * BK);

        bf16x8 a[4], b[4];
#pragma unroll
        for (int mi = 0; mi < 4; ++mi)
            a[mi] = *(const bf16x8*)(&As[cur][(wr * 64 + mi * 16 + lr) * BK + hi * 8]);
#pragma unroll
        for (int ni = 0; ni < 4; ++ni)
            b[ni] = *(const bf16x8*)(&Bs[cur][(wc * 64 + ni * 16 + lr) * BK + hi * 8]);

#pragma unroll
        for (int mi = 0; mi < 4; ++mi)
#pragma unroll
            for (int ni = 0; ni < 4; ++ni)
                acc[mi][ni] = __builtin_amdgcn_mfma_f32_16x16x32_bf16(
                    a[mi], b[ni], acc[mi][ni], 0, 0, 0);

        __syncthreads();
        cur ^= 1;
    }

    // store u (bf16). C/D layout: col = lane&15, row = (lane>>4)*4 + reg
    const int colbase = cb + wc * 64 + lr;
    const int rowbase = rb + wr * 64 + hi * 4;
#pragma unroll
    for (int mi = 0; mi < 4; ++mi) {
#pragma unroll
        for (int jj = 0; jj < 4; ++jj) {
            __bf16* urow = u + (size_t)(rowbase + mi * 16 + jj) * E_DIM + colbase;
#pragma unroll
            for (int ni = 0; ni < 4; ++ni)
                urow[ni * 16] = (__bf16)acc[mi][ni][jj];
        }
    }
}

// Streaming: one wave per row. delta_r = sum_c u[r][c]*(Ais-Aem)[r][c];
// hinge; 4 rows/block -> one partial per block.
__global__ __launch_bounds__(256)
void dot_hinge(const __bf16* __restrict__ u,
               const float* __restrict__ Ais, const float* __restrict__ Aem,
               float* __restrict__ partial) {
    const int lane = threadIdx.x & 63;
    const int wv   = threadIdx.x >> 6;
    const int r    = blockIdx.x * 4 + wv;

    const __bf16* ur = u + (size_t)r * E_DIM + lane * 16;
    const float*  pi = Ais + (size_t)r * E_DIM + lane * 16;
    const float*  pe = Aem + (size_t)r * E_DIM + lane * 16;

    bf16x8 u0 = *(const bf16x8*)(ur);
    bf16x8 u1 = *(const bf16x8*)(ur + 8);
    float s = 0.f;
#pragma unroll
    for (int j = 0; j < 8; ++j) {
        s += (float)u0[j] * (pi[j]     - pe[j]);
        s += (float)u1[j] * (pi[j + 8] - pe[j + 8]);
    }
    s += __shfl_xor(s, 1);
    s += __shfl_xor(s, 2);
    s += __shfl_xor(s, 4);
    s += __shfl_xor(s, 8);
    s += __shfl_xor(s, 16);
    s += __shfl_xor(s, 32);

    __shared__ float wsum[4];
    if (lane == 0) wsum[wv] = fmaxf(MARGIN + s, 0.f);
    __syncthreads();
    if (threadIdx.x == 0)
        partial[blockIdx.x] = wsum[0] + wsum[1] + wsum[2] + wsum[3];
}

__global__ void final_sum(const float* __restrict__ partial, float* __restrict__ out) {
    float s = 0.f;
    for (int i = threadIdx.x; i < 2048; i += 256) s += partial[i];
#pragma unroll
    for (int off = 32; off > 0; off >>= 1) s += __shfl_down(s, off);
    __shared__ float wsum[4];
    int lane = threadIdx.x & 63, w = threadIdx.x >> 6;
    if (lane == 0) wsum[w] = s;
    __syncthreads();
    if (threadIdx.x == 0) out[0] = wsum[0] + wsum[1] + wsum[2] + wsum[3];
}

extern "C" void kernel_launch(void* const* d_in, const int* in_sizes, int n_in,
                              void* d_out, int out_size, void* d_ws, size_t ws_size,
                              hipStream_t stream) {
    const float* A_is = (const float*)d_in[0];
    const float* A_em = (const float*)d_in[1];
    const float* m    = (const float*)d_in[2];
    const float* tr_m = (const float*)d_in[3];
    const float* W    = (const float*)d_in[4];
    // d_in[5] = b : cancels in diag_is - diag_em, unused.
    float* out = (float*)d_out;

    char* ws = (char*)d_ws;
    __bf16* c       = (__bf16*)ws;                               // [0,16M)
    __bf16* wt      = (__bf16*)(ws + (size_t)16 * 1024 * 1024);  // [16M,18M)
    __bf16* u       = (__bf16*)(ws + (size_t)18 * 1024 * 1024);  // [18M,34M)
    float*  partial = (float*) (ws + (size_t)34 * 1024 * 1024);  // 8 KiB

    prep_c<<<4096, 256, 0, stream>>>(m, tr_m, c);
    transpose_w<<<dim3(32, 32), dim3(32, 32), 0, stream>>>(W, wt);
    gemm_u<<<512, 256, 0, stream>>>(c, wt, u);
    dot_hinge<<<2048, 256, 0, stream>>>(u, A_is, A_em, partial);
    final_sum<<<1, 256, 0, stream>>>(partial, out);
}

// Round 8
// 61.232 us; speedup vs baseline: 1.1652x; 1.0791x over previous
//
#include <hip/hip_runtime.h>
#include <hip/hip_bf16.h>

#define B_ROWS 8192
#define E_DIM  1024
#define MARGIN 0.2f

#define BM 128
#define BN 128
#define BK 32
#define NSTEPS (E_DIM / BK)   // 32

typedef __bf16 bf16x8 __attribute__((ext_vector_type(8)));
typedef float  f32x4  __attribute__((ext_vector_type(4)));

__device__ __forceinline__ void gload_lds16(const void* g, void* l) {
    __builtin_amdgcn_global_load_lds(
        (__attribute__((address_space(1))) void*)(g),
        (__attribute__((address_space(3))) void*)(l),
        16, 0, 0);
}

#define GATE4() do { asm volatile("s_waitcnt vmcnt(4)" ::: "memory"); \
                     __builtin_amdgcn_sched_barrier(0); } while (0)
#define GATE0() do { asm volatile("s_waitcnt vmcnt(0)" ::: "memory"); \
                     __builtin_amdgcn_sched_barrier(0); } while (0)
#define RBAR()  do { __builtin_amdgcn_s_barrier(); \
                     __builtin_amdgcn_sched_barrier(0); } while (0)
#define LGKM0() do { asm volatile("s_waitcnt lgkmcnt(0)" ::: "memory"); \
                     __builtin_amdgcn_sched_barrier(0); } while (0)

// Combined prep pass: blocks [0,4096) compute c = 0.4*m + 0.6*tr_m (bf16);
// blocks [4096,5120) transpose W -> Wt[n][e] bf16.
__global__ __launch_bounds__(256)
void prep_combo(const float* __restrict__ m, const float* __restrict__ trm,
                __bf16* __restrict__ c,
                const float* __restrict__ W, __bf16* __restrict__ Wt) {
    __shared__ float tile[32][33];
    if (blockIdx.x < 4096) {
        size_t i = ((size_t)blockIdx.x * blockDim.x + threadIdx.x) * 8;
        float4 m0 = *(const float4*)(m + i);
        float4 m1 = *(const float4*)(m + i + 4);
        float4 t0 = *(const float4*)(trm + i);
        float4 t1 = *(const float4*)(trm + i + 4);
        bf16x8 v;
        v[0] = (__bf16)(0.4f*m0.x + 0.6f*t0.x);
        v[1] = (__bf16)(0.4f*m0.y + 0.6f*t0.y);
        v[2] = (__bf16)(0.4f*m0.z + 0.6f*t0.z);
        v[3] = (__bf16)(0.4f*m0.w + 0.6f*t0.w);
        v[4] = (__bf16)(0.4f*m1.x + 0.6f*t1.x);
        v[5] = (__bf16)(0.4f*m1.y + 0.6f*t1.y);
        v[6] = (__bf16)(0.4f*m1.z + 0.6f*t1.z);
        v[7] = (__bf16)(0.4f*m1.w + 0.6f*t1.w);
        *(bf16x8*)(c + i) = v;
    } else {
        const int tb = blockIdx.x - 4096;       // 1024 tiles of 32x32
        const int bx = (tb & 31) * 32;          // n base
        const int by = (tb >> 5) * 32;          // e base
        const int tx = threadIdx.x & 31;
        const int ty0 = threadIdx.x >> 5;       // 8 rows/thread
#pragma unroll
        for (int r = 0; r < 32; r += 8)
            tile[r + ty0][tx] = W[(size_t)(by + r + ty0) * E_DIM + bx + tx];
        __syncthreads();
#pragma unroll
        for (int r = 0; r < 32; r += 8)
            Wt[(size_t)(bx + r + ty0) * E_DIM + by + tx] = (__bf16)tile[tx][r + ty0];
    }
}

// u = c @ Wt^T with ring-of-3 LDS staging, raw barriers and COUNTED vmcnt
// gates (never drained mid-loop). Each thread stages exactly 4 x 16B per
// tile (2 A + 2 B), so per-wave vmcnt(4) at iter t certifies tile t
// (newest 4 outstanding = tile t+1's). Tile t's loads fly iters t-2..t.
// Fused epilogue: rowwise dot with (A_is - A_em), atomicAdd into delta[].
__global__ __launch_bounds__(256)
void gemm_dot(const __bf16* __restrict__ Cm, const __bf16* __restrict__ Wt,
              const float* __restrict__ Ais, const float* __restrict__ Aem,
              float* __restrict__ delta) {
    __shared__ __bf16 As[3][BM * BK];   // 3 x 8 KiB, linear
    __shared__ __bf16 Bs[3][BN * BK];   // 3 x 8 KiB, linear

    const int tid  = threadIdx.x;
    const int lane = tid & 63;
    const int wave = tid >> 6;
    const int lr   = lane & 15;
    const int hi   = lane >> 4;
    const int wr   = wave >> 1, wc = wave & 1;

    // XCD swizzle: xcd owns 8 row-panels x all 8 colb ->
    // per-XCD L2 set = 8 c-panels (2 MiB) + Wt (2 MiB).
    const int bid  = blockIdx.x;
    const int xcd  = bid & 7;
    const int q    = bid >> 3;
    const int rb   = (xcd * 8 + (q >> 3)) * BM;
    const int cb   = (q & 7) * BN;

    auto stage = [&](int slot, int k0) {
#pragma unroll
        for (int i = 0; i < 2; ++i) {
            int off = i * 4096 + tid * 16;   // byte offset in 8 KiB tile
            int row = off >> 6;              // 64 B per 32-bf16 row
            int kb  = off & 63;
            gload_lds16((const char*)Cm + ((size_t)(rb + row) * E_DIM + k0) * 2 + kb,
                        (char*)(&As[slot][0]) + off);
            gload_lds16((const char*)Wt + ((size_t)(cb + row) * E_DIM + k0) * 2 + kb,
                        (char*)(&Bs[slot][0]) + off);
        }
    };

    f32x4 acc[4][4] = {};

    // prologue: tiles 0,1 in flight (8 outstanding per thread)
    stage(0, 0);
    stage(1, BK);

    int s0 = 0, s1 = 1, s2 = 2;   // s0 = current tile's slot
    for (int t = 0; t < NSTEPS; ++t) {
        // certify tile t: newest <=4 outstanding are tile t+1's
        if (t + 1 < NSTEPS) GATE4(); else GATE0();
        RBAR();   // all waves certified their share of tile t

        bf16x8 a[4], b[4];
#pragma unroll
        for (int mi = 0; mi < 4; ++mi)
            a[mi] = *(const bf16x8*)(&As[s0][(wr * 64 + mi * 16 + lr) * BK + hi * 8]);
#pragma unroll
        for (int ni = 0; ni < 4; ++ni)
            b[ni] = *(const bf16x8*)(&Bs[s0][(wc * 64 + ni * 16 + lr) * BK + hi * 8]);
        LGKM0();  // own reads done before slot s2 reuse below & before MFMA

        // stage tile t+2 into slot s2 (= slot of tile t-1; all waves passed
        // the barrier above, so their reads of t-1 are complete)
        if (t + 2 < NSTEPS) stage(s2, (t + 2) * BK);

        __builtin_amdgcn_s_setprio(1);
#pragma unroll
        for (int mi = 0; mi < 4; ++mi)
#pragma unroll
            for (int ni = 0; ni < 4; ++ni)
                acc[mi][ni] = __builtin_amdgcn_mfma_f32_16x16x32_bf16(
                    a[mi], b[ni], acc[mi][ni], 0, 0, 0);
        __builtin_amdgcn_s_setprio(0);

        int tmp = s0; s0 = s1; s1 = s2; s2 = tmp;   // rotate ring
    }

    // epilogue: delta[r] += sum_col u[r][col] * (Ais - Aem)[r][col]
    // C/D layout (16x16x32): col = lane&15, row = (lane>>4)*4 + reg
    const int colbase = cb + wc * 64 + lr;
    const int rowbase = rb + wr * 64 + hi * 4;
#pragma unroll
    for (int mi = 0; mi < 4; ++mi) {
#pragma unroll
        for (int jj = 0; jj < 4; ++jj) {
            const int r = rowbase + mi * 16 + jj;
            float v = 0.f;
#pragma unroll
            for (int ni = 0; ni < 4; ++ni) {
                const size_t idx = (size_t)r * E_DIM + colbase + ni * 16;
                v += acc[mi][ni][jj] * (Ais[idx] - Aem[idx]);
            }
            v += __shfl_xor(v, 1);
            v += __shfl_xor(v, 2);
            v += __shfl_xor(v, 4);
            v += __shfl_xor(v, 8);
            if (lr == 0) atomicAdd(&delta[r], v);
        }
    }
}

__global__ void hinge_sum(const float* __restrict__ delta, float* __restrict__ out) {
    float s = 0.f;
    for (int i = threadIdx.x; i < B_ROWS; i += 256)
        s += fmaxf(MARGIN + delta[i], 0.f);
#pragma unroll
    for (int off = 32; off > 0; off >>= 1) s += __shfl_down(s, off);
    __shared__ float wsum[4];
    int lane = threadIdx.x & 63, w = threadIdx.x >> 6;
    if (lane == 0) wsum[w] = s;
    __syncthreads();
    if (threadIdx.x == 0) out[0] = wsum[0] + wsum[1] + wsum[2] + wsum[3];
}

extern "C" void kernel_launch(void* const* d_in, const int* in_sizes, int n_in,
                              void* d_out, int out_size, void* d_ws, size_t ws_size,
                              hipStream_t stream) {
    const float* A_is = (const float*)d_in[0];
    const float* A_em = (const float*)d_in[1];
    const float* m    = (const float*)d_in[2];
    const float* tr_m = (const float*)d_in[3];
    const float* W    = (const float*)d_in[4];
    // d_in[5] = b : cancels in diag_is - diag_em, unused.
    float* out = (float*)d_out;

    char* ws = (char*)d_ws;
    __bf16* c     = (__bf16*)ws;                              // 16 MiB
    __bf16* wt    = (__bf16*)(ws + (size_t)16 * 1024 * 1024); //  2 MiB
    float*  delta = (float*) (ws + (size_t)18 * 1024 * 1024); // 32 KiB

    hipMemsetAsync(delta, 0, B_ROWS * sizeof(float), stream);
    prep_combo<<<5120, 256, 0, stream>>>(m, tr_m, c, W, wt);
    gemm_dot<<<512, 256, 0, stream>>>(c, wt, A_is, A_em, delta);
    hinge_sum<<<1, 256, 0, stream>>>(delta, out);
}